// Round 8
// baseline (247.440 us; speedup 1.0000x reference)
//
#include <hip/hip_runtime.h>

#define TT 512
#define BB 256
#define DD 2048
#define DQ 2049                   // D + Q (Q == 1)
#define CH_T 128                  // timesteps per chunk (4 chunks)
#define CH_ROWS (CH_T * BB)       // 32768 rows per chunk
#define RPW 8                     // rows per wave
#define CH_WAVES (CH_ROWS / RPW)  // 4096 waves per chunk
#define CH_BLOCKS (CH_WAVES / 4)  // 1024 blocks per chunk

typedef float f32x4 __attribute__((ext_vector_type(4)));

// system-scope non-temporal load: bypass L1 and L2 allocation (read-once x)
__device__ __forceinline__ void ldg_nt(f32x4& d, const float* p) {
    asm volatile("global_load_dwordx4 %0, %1, off sc0 sc1 nt"
                 : "=v"(d) : "v"(p));
}
// counted waits; waited regs are read-write operands so consumers are
// data-ordered AFTER the wait (rule-18 hoist hazard avoided by dataflow).
__device__ __forceinline__ void wait_vm12(f32x4& a, f32x4& b, f32x4& c, f32x4& d) {
    asm volatile("s_waitcnt vmcnt(12)" : "+v"(a), "+v"(b), "+v"(c), "+v"(d));
}
__device__ __forceinline__ void wait_vm8(f32x4& a, f32x4& b, f32x4& c, f32x4& d) {
    asm volatile("s_waitcnt vmcnt(8)" : "+v"(a), "+v"(b), "+v"(c), "+v"(d));
}
__device__ __forceinline__ void wait_vm4(f32x4& a, f32x4& b, f32x4& c, f32x4& d) {
    asm volatile("s_waitcnt vmcnt(4)" : "+v"(a), "+v"(b), "+v"(c), "+v"(d));
}
__device__ __forceinline__ void wait_vm0(f32x4& a, f32x4& b, f32x4& c, f32x4& d) {
    asm volatile("s_waitcnt vmcnt(0)" : "+v"(a), "+v"(b), "+v"(c), "+v"(d));
}

__device__ __forceinline__ float frcp(float x) { return __builtin_amdgcn_rcpf(x); }
__device__ __forceinline__ float ftanh(float x) {
    const float e = exp2f(x * 2.8853900817779268f);   // e^(2x)
    return 1.f - 2.f * frcp(1.f + e);
}
__device__ __forceinline__ float fsig(float x) {
    const float e = exp2f(-x * 1.4426950408889634f);  // e^-x
    return frcp(1.f + e);
}

// ---- GEMM part: one wave = 8 rows, 4-deep (16-load) pipeline --------------
// pre'[row][g] = al[g] * (dot(x,lw[g]) + lb[g]) + be[g]
__device__ __forceinline__ void gemm_part(
    const float* __restrict__ x, const float* __restrict__ lw,
    const float* __restrict__ lb, const float* __restrict__ ew,
    const float* __restrict__ ebv, const float* __restrict__ rx,
    f32x4* __restrict__ pre, int wave_base, int block_off)
{
    __shared__ f32x4 wlds[2048];    // [it 0..7][g 0..3][lane 0..63]
    float* wldsf = (float*)wlds;
    for (int j = threadIdx.x; j < 8192; j += 256) {
        const int it = j >> 10;
        const int g  = (j >> 8) & 3;
        wldsf[j] = lw[g * DQ + it * 256 + (j & 255)];
    }
    __syncthreads();

    const int lane = threadIdx.x & 63;
    const int wid  = wave_base + (blockIdx.x - block_off) * 4 + (threadIdx.x >> 6);
    const int row0 = wid * RPW;

    float alv[4], bev[4], lbv[4];
#pragma unroll
    for (int g = 0; g < 4; ++g) {
        alv[g] = rx[g] * ew[g];
        bev[g] = rx[g] * ebv[g];
        lbv[g] = lb[g];
    }

    const float* xbp = x + (size_t)row0 * DD + lane * 4;

    // batch s (s = grp*8 + it, grp in {0,1}) loads rows grp*4..grp*4+3,
    // columns it*256..+255. 4 rotating buffers, 16 loads in flight.
    f32x4 xbuf[4][4];
#pragma unroll
    for (int s = 0; s < 3; ++s) {
        const int g0 = s >> 3, it0 = s & 7;
#pragma unroll
        for (int r = 0; r < 4; ++r)
            ldg_nt(xbuf[s][r], xbp + (size_t)(g0 * 4 + r) * DD + it0 * 256);
    }

    float a[4][4];
#pragma unroll
    for (int s = 0; s < 16; ++s) {
        const int grp = s >> 3, it = s & 7;
        if (it == 0) {
#pragma unroll
            for (int r = 0; r < 4; ++r)
#pragma unroll
                for (int q = 0; q < 4; ++q) a[r][q] = 0.f;
        }
        if (s + 3 < 16) {
            const int s2 = s + 3, g2 = s2 >> 3, it2 = s2 & 7;
#pragma unroll
            for (int r = 0; r < 4; ++r)
                ldg_nt(xbuf[s2 & 3][r],
                       xbp + (size_t)(g2 * 4 + r) * DD + it2 * 256);
        }
        // wait until batch s complete: 16 in flight steady -> vmcnt(12)
        if (s < 13)
            wait_vm12(xbuf[s & 3][0], xbuf[s & 3][1], xbuf[s & 3][2], xbuf[s & 3][3]);
        else if (s == 13)
            wait_vm8(xbuf[s & 3][0], xbuf[s & 3][1], xbuf[s & 3][2], xbuf[s & 3][3]);
        else if (s == 14)
            wait_vm4(xbuf[s & 3][0], xbuf[s & 3][1], xbuf[s & 3][2], xbuf[s & 3][3]);
        else
            wait_vm0(xbuf[s & 3][0], xbuf[s & 3][1], xbuf[s & 3][2], xbuf[s & 3][3]);

        const f32x4 w0 = wlds[(it * 4 + 0) * 64 + lane];
        const f32x4 w1 = wlds[(it * 4 + 1) * 64 + lane];
        const f32x4 w2 = wlds[(it * 4 + 2) * 64 + lane];
        const f32x4 w3 = wlds[(it * 4 + 3) * 64 + lane];
#pragma unroll
        for (int r = 0; r < 4; ++r) {
            const f32x4 xv = xbuf[s & 3][r];
            a[r][0] += xv[0] * w0[0] + xv[1] * w0[1] + xv[2] * w0[2] + xv[3] * w0[3];
            a[r][1] += xv[0] * w1[0] + xv[1] * w1[1] + xv[2] * w1[2] + xv[3] * w1[3];
            a[r][2] += xv[0] * w2[0] + xv[1] * w2[1] + xv[2] * w2[2] + xv[3] * w2[3];
            a[r][3] += xv[0] * w3[0] + xv[1] * w3[1] + xv[2] * w3[2] + xv[3] * w3[3];
        }

        if (it == 7) {
#pragma unroll
            for (int st = 32; st >= 1; st >>= 1) {
#pragma unroll
                for (int r = 0; r < 4; ++r)
#pragma unroll
                    for (int q = 0; q < 4; ++q)
                        a[r][q] += __shfl_xor(a[r][q], st);
            }
            if (lane == 0) {
#pragma unroll
                for (int r = 0; r < 4; ++r) {
                    f32x4 o = {alv[0] * (a[r][0] + lbv[0]) + bev[0],
                               alv[1] * (a[r][1] + lbv[1]) + bev[1],
                               alv[2] * (a[r][2] + lbv[2]) + bev[2],
                               alv[3] * (a[r][3] + lbv[3]) + bev[3]};
                    pre[row0 + grp * 4 + r] = o;
                }
            }
        }
    }
}

// ---- scan part: CH_T steps, one thread per batch element ------------------
__device__ __forceinline__ void scan_part(
    const f32x4* __restrict__ pre, const float* __restrict__ lw,
    const float* __restrict__ ew, const float* __restrict__ ebv,
    const float* __restrict__ rx, const float* __restrict__ mw,
    const float* __restrict__ mb, float* __restrict__ out,
    float* __restrict__ hc, int t0)
{
    const int b = threadIdx.x;

    float aw[4], mww[4], mbb[4];
#pragma unroll
    for (int g = 0; g < 4; ++g) {
        aw[g]  = rx[g] * ew[g] * lw[g * DQ + DD];   // al[g] * whx[g]
        mww[g] = mw[g];
        mbb[g] = mb[g];
    }

    float h, c;
    if (t0 == 0) { h = 0.f; c = 0.f; }
    else         { h = hc[b]; c = hc[BB + b]; }

    f32x4 cur[8], nxt[8];
#pragma unroll
    for (int j = 0; j < 8; ++j) cur[j] = pre[(t0 + j) * BB + b];

    for (int tt = t0; tt < t0 + CH_T; tt += 8) {
        const int tn = tt + 8;
        if (tn < t0 + CH_T) {
#pragma unroll
            for (int j = 0; j < 8; ++j) nxt[j] = pre[(tn + j) * BB + b];
        }
#pragma unroll
        for (int j = 0; j < 8; ++j) {
            const f32x4 pc = cur[j];
            const float s0 = ftanh(fmaf(h, aw[0], pc[0]));
            const float s1 = ftanh(fmaf(h, aw[1], pc[1]));
            const float s2 = ftanh(fmaf(h, aw[2], pc[2]));
            const float s3 = ftanh(fmaf(h, aw[3], pc[3]));
            const float f  = fsig(fmaf(s0, mww[0], mbb[0]));
            const float i  = fsig(fmaf(s1, mww[1], mbb[1]));
            const float gg = ftanh(fmaf(s2, mww[2], mbb[2]));
            const float o  = fsig(fmaf(s3, mww[3], mbb[3]));
            c = f * c + i * gg;
            h = o * ftanh(c);
            out[(tt + j) * BB + b] = h;
        }
#pragma unroll
        for (int j = 0; j < 8; ++j) cur[j] = nxt[j];
    }

    hc[b]      = h;
    hc[BB + b] = c;
    if (t0 + CH_T == TT) {
        out[TT * BB + b]      = h;
        out[TT * BB + BB + b] = c;
    }
}

// ---- kernels --------------------------------------------------------------
__global__ __launch_bounds__(256) void k_gemm0(
    const float* __restrict__ x, const float* __restrict__ lw,
    const float* __restrict__ lb, const float* __restrict__ ew,
    const float* __restrict__ ebv, const float* __restrict__ rx,
    f32x4* __restrict__ pre)
{
    gemm_part(x, lw, lb, ew, ebv, rx, pre, 0, 0);
}

// block 0: scan chunk [scan_t0, scan_t0+CH_T) over pre written by PREVIOUS
// launch (kernel-boundary dependency — fully coherent). blocks >= 1: gemm of
// the NEXT chunk (disjoint pre rows).
__global__ __launch_bounds__(256) void k_mix(
    const float* __restrict__ x, const float* __restrict__ lw,
    const float* __restrict__ lb, const float* __restrict__ ew,
    const float* __restrict__ ebv, const float* __restrict__ rx,
    const float* __restrict__ mw, const float* __restrict__ mb,
    f32x4* __restrict__ pre, float* __restrict__ out,
    float* __restrict__ hc, int scan_t0, int wave_base)
{
    if (blockIdx.x == 0)
        scan_part(pre, lw, ew, ebv, rx, mw, mb, out, hc, scan_t0);
    else
        gemm_part(x, lw, lb, ew, ebv, rx, pre, wave_base, 1);
}

extern "C" void kernel_launch(void* const* d_in, const int* in_sizes, int n_in,
                              void* d_out, int out_size, void* d_ws, size_t ws_size,
                              hipStream_t stream) {
    const float* x   = (const float*)d_in[0];   // [512,256,2048]
    const float* lw  = (const float*)d_in[1];   // [4,1,2049]
    const float* lb  = (const float*)d_in[2];   // [4,1]
    const float* ew  = (const float*)d_in[3];   // [4,1,1]
    const float* ebv = (const float*)d_in[4];   // [4,1]
    const float* rx  = (const float*)d_in[5];   // [4]
    const float* mw  = (const float*)d_in[6];   // [4,1,1]
    const float* mb  = (const float*)d_in[7];   // [4,1]
    float* out = (float*)d_out;

    f32x4* pre = (f32x4*)d_ws;                              // 2 MiB
    float* hc  = (float*)((char*)d_ws + (size_t)TT * BB * 16);  // 2 KB

    k_gemm0<<<CH_BLOCKS, 256, 0, stream>>>(x, lw, lb, ew, ebv, rx, pre);
    k_mix<<<CH_BLOCKS + 1, 256, 0, stream>>>(x, lw, lb, ew, ebv, rx, mw, mb,
                                             pre, out, hc, 0, CH_WAVES);
    k_mix<<<CH_BLOCKS + 1, 256, 0, stream>>>(x, lw, lb, ew, ebv, rx, mw, mb,
                                             pre, out, hc, CH_T, 2 * CH_WAVES);
    k_mix<<<CH_BLOCKS + 1, 256, 0, stream>>>(x, lw, lb, ew, ebv, rx, mw, mb,
                                             pre, out, hc, 2 * CH_T, 3 * CH_WAVES);
    k_mix<<<1, 256, 0, stream>>>(x, lw, lb, ew, ebv, rx, mw, mb,
                                 pre, out, hc, 3 * CH_T, 0);
}

// Round 9
// 240.108 us; speedup vs baseline: 1.0305x; 1.0305x over previous
//
#include <hip/hip_runtime.h>

#define TT 512
#define BB 256
#define DD 2048
#define DQ 2049                   // D + Q (Q == 1)
#define CH_T 128                  // timesteps per chunk (4 chunks)
#define CH_ROWS (CH_T * BB)       // 32768 rows per chunk
#define RPW 8                     // rows per wave
#define CH_WAVES (CH_ROWS / RPW)  // 4096 waves per chunk
#define CH_BLOCKS (CH_WAVES / 4)  // 1024 blocks per chunk

typedef float f32x4 __attribute__((ext_vector_type(4)));

// system-scope non-temporal load: bypass L1 and L2 allocation (read-once x)
__device__ __forceinline__ void ldg_nt(f32x4& d, const float* p) {
    asm volatile("global_load_dwordx4 %0, %1, off sc0 sc1 nt"
                 : "=v"(d) : "v"(p));
}
// counted waits; waited regs are read-write operands so consumers are
// data-ordered AFTER the wait (rule-18 hoist hazard avoided by dataflow).
__device__ __forceinline__ void wait_vm8(f32x4& a, f32x4& b, f32x4& c, f32x4& d) {
    asm volatile("s_waitcnt vmcnt(8)" : "+v"(a), "+v"(b), "+v"(c), "+v"(d));
}
__device__ __forceinline__ void wait_vm4(f32x4& a, f32x4& b, f32x4& c, f32x4& d) {
    asm volatile("s_waitcnt vmcnt(4)" : "+v"(a), "+v"(b), "+v"(c), "+v"(d));
}
__device__ __forceinline__ void wait_vm0(f32x4& a, f32x4& b, f32x4& c, f32x4& d) {
    asm volatile("s_waitcnt vmcnt(0)" : "+v"(a), "+v"(b), "+v"(c), "+v"(d));
}

__device__ __forceinline__ float frcp(float x) { return __builtin_amdgcn_rcpf(x); }
__device__ __forceinline__ float ftanh(float x) {
    const float e = exp2f(x * 2.8853900817779268f);   // e^(2x)
    return 1.f - 2.f * frcp(1.f + e);
}
__device__ __forceinline__ float fsig(float x) {
    const float e = exp2f(-x * 1.4426950408889634f);  // e^-x
    return frcp(1.f + e);
}

// ---- GEMM part: one wave = 8 rows, 3-deep (12-load) pipeline --------------
// pre'[row][g] = al[g] * (dot(x,lw[g]) + lb[g]) + be[g]
__device__ __forceinline__ void gemm_part(
    const float* __restrict__ x, const float* __restrict__ lw,
    const float* __restrict__ lb, const float* __restrict__ ew,
    const float* __restrict__ ebv, const float* __restrict__ rx,
    f32x4* __restrict__ pre, int wave_base, int block_off)
{
    __shared__ f32x4 wlds[2048];    // [it 0..7][g 0..3][lane 0..63]
    float* wldsf = (float*)wlds;
    for (int j = threadIdx.x; j < 8192; j += 256) {
        const int it = j >> 10;
        const int g  = (j >> 8) & 3;
        wldsf[j] = lw[g * DQ + it * 256 + (j & 255)];
    }
    __syncthreads();

    const int lane = threadIdx.x & 63;
    const int wid  = wave_base + (blockIdx.x - block_off) * 4 + (threadIdx.x >> 6);
    const int row0 = wid * RPW;

    float alv[4], bev[4], lbv[4];
#pragma unroll
    for (int g = 0; g < 4; ++g) {
        alv[g] = rx[g] * ew[g];
        bev[g] = rx[g] * ebv[g];
        lbv[g] = lb[g];
    }

    const float* xbp = x + (size_t)row0 * DD + lane * 4;

    // batch s (s = grp*8 + it, grp in {0,1}) loads rows grp*4..grp*4+3,
    // columns it*256..+255. 3 rotating buffers, 12 loads in flight.
    f32x4 xbuf[3][4];
#pragma unroll
    for (int r = 0; r < 4; ++r) ldg_nt(xbuf[0][r], xbp + (size_t)r * DD);
#pragma unroll
    for (int r = 0; r < 4; ++r) ldg_nt(xbuf[1][r], xbp + (size_t)r * DD + 256);

    float a[4][4];
#pragma unroll
    for (int s = 0; s < 16; ++s) {
        const int grp = s >> 3, it = s & 7;
        if (it == 0) {
#pragma unroll
            for (int r = 0; r < 4; ++r)
#pragma unroll
                for (int q = 0; q < 4; ++q) a[r][q] = 0.f;
        }
        if (s + 2 < 16) {
            const int s2 = s + 2, g2 = s2 >> 3, it2 = s2 & 7;
#pragma unroll
            for (int r = 0; r < 4; ++r)
                ldg_nt(xbuf[s2 % 3][r],
                       xbp + (size_t)(g2 * 4 + r) * DD + it2 * 256);
        }
        // steady state: 12 loads in flight; wait until batch s complete.
        if (s < 14)
            wait_vm8(xbuf[s % 3][0], xbuf[s % 3][1], xbuf[s % 3][2], xbuf[s % 3][3]);
        else if (s == 14)
            wait_vm4(xbuf[s % 3][0], xbuf[s % 3][1], xbuf[s % 3][2], xbuf[s % 3][3]);
        else
            wait_vm0(xbuf[s % 3][0], xbuf[s % 3][1], xbuf[s % 3][2], xbuf[s % 3][3]);

        const f32x4 w0 = wlds[(it * 4 + 0) * 64 + lane];
        const f32x4 w1 = wlds[(it * 4 + 1) * 64 + lane];
        const f32x4 w2 = wlds[(it * 4 + 2) * 64 + lane];
        const f32x4 w3 = wlds[(it * 4 + 3) * 64 + lane];
#pragma unroll
        for (int r = 0; r < 4; ++r) {
            const f32x4 xv = xbuf[s % 3][r];
            a[r][0] += xv[0] * w0[0] + xv[1] * w0[1] + xv[2] * w0[2] + xv[3] * w0[3];
            a[r][1] += xv[0] * w1[0] + xv[1] * w1[1] + xv[2] * w1[2] + xv[3] * w1[3];
            a[r][2] += xv[0] * w2[0] + xv[1] * w2[1] + xv[2] * w2[2] + xv[3] * w2[3];
            a[r][3] += xv[0] * w3[0] + xv[1] * w3[1] + xv[2] * w3[2] + xv[3] * w3[3];
        }

        if (it == 7) {
#pragma unroll
            for (int st = 32; st >= 1; st >>= 1) {
#pragma unroll
                for (int r = 0; r < 4; ++r)
#pragma unroll
                    for (int q = 0; q < 4; ++q)
                        a[r][q] += __shfl_xor(a[r][q], st);
            }
            if (lane == 0) {
#pragma unroll
                for (int r = 0; r < 4; ++r) {
                    f32x4 o = {alv[0] * (a[r][0] + lbv[0]) + bev[0],
                               alv[1] * (a[r][1] + lbv[1]) + bev[1],
                               alv[2] * (a[r][2] + lbv[2]) + bev[2],
                               alv[3] * (a[r][3] + lbv[3]) + bev[3]};
                    pre[row0 + grp * 4 + r] = o;
                }
            }
        }
    }
}

// ---- scan part: CH_T steps, one thread per batch element ------------------
__device__ __forceinline__ void scan_part(
    const f32x4* __restrict__ pre, const float* __restrict__ lw,
    const float* __restrict__ ew, const float* __restrict__ ebv,
    const float* __restrict__ rx, const float* __restrict__ mw,
    const float* __restrict__ mb, float* __restrict__ out,
    float* __restrict__ hc, int t0)
{
    const int b = threadIdx.x;

    float aw[4], mww[4], mbb[4];
#pragma unroll
    for (int g = 0; g < 4; ++g) {
        aw[g]  = rx[g] * ew[g] * lw[g * DQ + DD];   // al[g] * whx[g]
        mww[g] = mw[g];
        mbb[g] = mb[g];
    }

    float h, c;
    if (t0 == 0) { h = 0.f; c = 0.f; }
    else         { h = hc[b]; c = hc[BB + b]; }

    f32x4 cur[8], nxt[8];
#pragma unroll
    for (int j = 0; j < 8; ++j) cur[j] = pre[(t0 + j) * BB + b];

    for (int tt = t0; tt < t0 + CH_T; tt += 8) {
        const int tn = tt + 8;
        if (tn < t0 + CH_T) {
#pragma unroll
            for (int j = 0; j < 8; ++j) nxt[j] = pre[(tn + j) * BB + b];
        }
#pragma unroll
        for (int j = 0; j < 8; ++j) {
            const f32x4 pc = cur[j];
            const float s0 = ftanh(fmaf(h, aw[0], pc[0]));
            const float s1 = ftanh(fmaf(h, aw[1], pc[1]));
            const float s2 = ftanh(fmaf(h, aw[2], pc[2]));
            const float s3 = ftanh(fmaf(h, aw[3], pc[3]));
            const float f  = fsig(fmaf(s0, mww[0], mbb[0]));
            const float i  = fsig(fmaf(s1, mww[1], mbb[1]));
            const float gg = ftanh(fmaf(s2, mww[2], mbb[2]));
            const float o  = fsig(fmaf(s3, mww[3], mbb[3]));
            c = f * c + i * gg;
            h = o * ftanh(c);
            out[(tt + j) * BB + b] = h;
        }
#pragma unroll
        for (int j = 0; j < 8; ++j) cur[j] = nxt[j];
    }

    hc[b]      = h;
    hc[BB + b] = c;
    if (t0 + CH_T == TT) {
        out[TT * BB + b]      = h;
        out[TT * BB + BB + b] = c;
    }
}

// ---- kernels --------------------------------------------------------------
__global__ __launch_bounds__(256) void k_gemm0(
    const float* __restrict__ x, const float* __restrict__ lw,
    const float* __restrict__ lb, const float* __restrict__ ew,
    const float* __restrict__ ebv, const float* __restrict__ rx,
    f32x4* __restrict__ pre)
{
    gemm_part(x, lw, lb, ew, ebv, rx, pre, 0, 0);
}

// block 0: scan chunk [scan_t0, scan_t0+CH_T) over pre written by PREVIOUS
// launch (kernel-boundary dependency — fully coherent). blocks >= 1: gemm of
// the NEXT chunk (disjoint pre rows).
__global__ __launch_bounds__(256) void k_mix(
    const float* __restrict__ x, const float* __restrict__ lw,
    const float* __restrict__ lb, const float* __restrict__ ew,
    const float* __restrict__ ebv, const float* __restrict__ rx,
    const float* __restrict__ mw, const float* __restrict__ mb,
    f32x4* __restrict__ pre, float* __restrict__ out,
    float* __restrict__ hc, int scan_t0, int wave_base)
{
    if (blockIdx.x == 0)
        scan_part(pre, lw, ew, ebv, rx, mw, mb, out, hc, scan_t0);
    else
        gemm_part(x, lw, lb, ew, ebv, rx, pre, wave_base, 1);
}

extern "C" void kernel_launch(void* const* d_in, const int* in_sizes, int n_in,
                              void* d_out, int out_size, void* d_ws, size_t ws_size,
                              hipStream_t stream) {
    const float* x   = (const float*)d_in[0];   // [512,256,2048]
    const float* lw  = (const float*)d_in[1];   // [4,1,2049]
    const float* lb  = (const float*)d_in[2];   // [4,1]
    const float* ew  = (const float*)d_in[3];   // [4,1,1]
    const float* ebv = (const float*)d_in[4];   // [4,1]
    const float* rx  = (const float*)d_in[5];   // [4]
    const float* mw  = (const float*)d_in[6];   // [4,1,1]
    const float* mb  = (const float*)d_in[7];   // [4,1]
    float* out = (float*)d_out;

    f32x4* pre = (f32x4*)d_ws;                              // 2 MiB
    float* hc  = (float*)((char*)d_ws + (size_t)TT * BB * 16);  // 2 KB

    k_gemm0<<<CH_BLOCKS, 256, 0, stream>>>(x, lw, lb, ew, ebv, rx, pre);
    k_mix<<<CH_BLOCKS + 1, 256, 0, stream>>>(x, lw, lb, ew, ebv, rx, mw, mb,
                                             pre, out, hc, 0, CH_WAVES);
    k_mix<<<CH_BLOCKS + 1, 256, 0, stream>>>(x, lw, lb, ew, ebv, rx, mw, mb,
                                             pre, out, hc, CH_T, 2 * CH_WAVES);
    k_mix<<<CH_BLOCKS + 1, 256, 0, stream>>>(x, lw, lb, ew, ebv, rx, mw, mb,
                                             pre, out, hc, 2 * CH_T, 3 * CH_WAVES);
    k_mix<<<1, 256, 0, stream>>>(x, lw, lb, ew, ebv, rx, mw, mb,
                                 pre, out, hc, 3 * CH_T, 0);
}